// Round 2
// baseline (849.309 us; speedup 1.0000x reference)
//
#include <hip/hip_runtime.h>
#include <hip/hip_bf16.h>

typedef __bf16 bf16;
typedef __bf16 bf16x8 __attribute__((ext_vector_type(8)));
typedef float f32x4 __attribute__((ext_vector_type(4)));

#define B_    2
#define S_    2048
#define HD    2048
#define NH    16
#define DQK   192
#define DV    128
#define QR    1536
#define KVR   512
#define NTOK  4096
#define NKVB  4096   /* N_HEADS*(D_NOPE+D_V) */
#define NQB   3072   /* N_HEADS*D_QK */

static __device__ __forceinline__ void gload16(const void* g, void* l) {
  __builtin_amdgcn_global_load_lds(
      (const __attribute__((address_space(1))) void*)g,
      (__attribute__((address_space(3))) void*)l, 16, 0, 0);
}

// ---------------- f32 -> bf16 convert ----------------
__global__ __launch_bounds__(256) void cvt_bf16(const float* __restrict__ in,
                                                bf16* __restrict__ out, long n) {
  long i = ((long)blockIdx.x * 256 + threadIdx.x) * 4;
  if (i + 3 < n) {
    float4 v = *(const float4*)(in + i);
    out[i] = (bf16)v.x; out[i+1] = (bf16)v.y; out[i+2] = (bf16)v.z; out[i+3] = (bf16)v.w;
  }
}

// ---------------- transpose f32 [R][C] -> bf16 [Np][R], zero-pad rows >= C ----
__global__ __launch_bounds__(256) void transpose_cvt(const float* __restrict__ in,
                                                     bf16* __restrict__ out,
                                                     int R, int C, int Np) {
  __shared__ float tile[32][33];
  int c0 = blockIdx.x * 32;
  int r0 = blockIdx.y * 32;
  int tx = threadIdx.x & 31, ty = threadIdx.x >> 5;
#pragma unroll
  for (int i = 0; i < 4; ++i) {
    int r = r0 + ty + i * 8, c = c0 + tx;
    tile[ty + i * 8][tx] = (c < C) ? in[(long)r * C + c] : 0.f;
  }
  __syncthreads();
#pragma unroll
  for (int i = 0; i < 4; ++i) {
    int oc = c0 + ty + i * 8;
    if (oc < Np) out[(long)oc * R + r0 + tx] = (bf16)tile[tx][ty + i * 8];
  }
}

// ---------------- GEMM: C[M][N] = A[M][K] bf16 @ Bt[N][K] bf16 ----------------
// 128x128 tile, BK=32, 4 waves, global_load_lds(16B), mfma 16x16x32 bf16.
template <typename CT>
__global__ __launch_bounds__(256) void gemm_bf16(const bf16* __restrict__ A,
                                                 const bf16* __restrict__ Bt,
                                                 CT* __restrict__ C,
                                                 int M, int N, int K) {
  __shared__ bf16 As[128 * 32];
  __shared__ bf16 Bs[128 * 32];
  const int t = threadIdx.x;
  const int l = t & 63;
  const int w = t >> 6;
  const int m0 = blockIdx.y * 128;
  const int n0 = blockIdx.x * 128;
  const int wr = (w >> 1) * 64;
  const int wc = (w & 1) * 64;
  const int lr = l & 15;
  const int lg = l >> 4;

  f32x4 acc[4][4] = {};

  for (int k0 = 0; k0 < K; k0 += 32) {
    __syncthreads();
#pragma unroll
    for (int j = 0; j < 2; ++j) {
      int c = j * 256 + t;                 // chunk 0..511 (8 bf16 each)
      int row = c >> 2, kk = (c & 3) * 8;
      // wave-uniform LDS base: hardware writes base + lane*16
      bf16* abase = As + (j * 256 + w * 64) * 8;
      bf16* bbase = Bs + (j * 256 + w * 64) * 8;
      gload16(A  + (long)(m0 + row) * K + k0 + kk, abase);
      gload16(Bt + (long)(n0 + row) * K + k0 + kk, bbase);
    }
    __syncthreads();
    bf16x8 af[4], bfr[4];
#pragma unroll
    for (int m = 0; m < 4; ++m)
      af[m] = *(const bf16x8*)(As + (wr + m * 16 + lr) * 32 + lg * 8);
#pragma unroll
    for (int n = 0; n < 4; ++n)
      bfr[n] = *(const bf16x8*)(Bs + (wc + n * 16 + lr) * 32 + lg * 8);
#pragma unroll
    for (int m = 0; m < 4; ++m)
#pragma unroll
      for (int n = 0; n < 4; ++n)
        acc[m][n] = __builtin_amdgcn_mfma_f32_16x16x32_bf16(af[m], bfr[n], acc[m][n], 0, 0, 0);
  }
#pragma unroll
  for (int m = 0; m < 4; ++m)
#pragma unroll
    for (int n = 0; n < 4; ++n)
#pragma unroll
      for (int v = 0; v < 4; ++v) {
        int row = m0 + wr + m * 16 + lg * 4 + v;
        int col = n0 + wc + n * 16 + lr;
        C[(long)row * N + col] = (CT)acc[m][n][v];
      }
}

// ---------------- RMSNorm (q path): [NTOK][QR] bf16 -> bf16 -------------------
__global__ __launch_bounds__(256) void rmsnorm_q(const bf16* __restrict__ in,
                                                 const float* __restrict__ g,
                                                 bf16* __restrict__ out) {
  int row = blockIdx.x;
  const bf16* x = in + (long)row * QR;
  float ss = 0.f;
  for (int j = threadIdx.x; j < QR; j += 256) { float v = (float)x[j]; ss += v * v; }
#pragma unroll
  for (int m = 1; m < 64; m <<= 1) ss += __shfl_xor(ss, m);
  __shared__ float red[4];
  if ((threadIdx.x & 63) == 0) red[threadIdx.x >> 6] = ss;
  __syncthreads();
  ss = red[0] + red[1] + red[2] + red[3];
  float rs = rsqrtf(ss / QR + 1e-5f);
  for (int j = threadIdx.x; j < QR; j += 256)
    out[(long)row * QR + j] = (bf16)((float)x[j] * rs * g[j]);
}

// ---------------- kv prep: RMSNorm latent + RoPE k_rope broadcast -------------
__global__ __launch_bounds__(256) void kv_prep(const bf16* __restrict__ kv_a,  // [NTOK][640]
                                               const float* __restrict__ g,    // [512]
                                               const int* __restrict__ pos,
                                               const float* __restrict__ cosT, // [S][32]
                                               const float* __restrict__ sinT,
                                               bf16* __restrict__ kv_l,        // [NTOK][512]
                                               bf16* __restrict__ k_bhsd) {    // [B][H][S][192]
  int row = blockIdx.x;
  int b = row / S_, s = row % S_;
  const bf16* x = kv_a + (long)row * 640;
  float ss = 0.f;
  for (int j = threadIdx.x; j < KVR; j += 256) { float v = (float)x[j]; ss += v * v; }
#pragma unroll
  for (int m = 1; m < 64; m <<= 1) ss += __shfl_xor(ss, m);
  __shared__ float red[4];
  if ((threadIdx.x & 63) == 0) red[threadIdx.x >> 6] = ss;
  __syncthreads();
  ss = red[0] + red[1] + red[2] + red[3];
  float rs = rsqrtf(ss / KVR + 1e-5f);
  for (int j = threadIdx.x; j < KVR; j += 256)
    kv_l[(long)row * KVR + j] = (bf16)((float)x[j] * rs * g[j]);
  if (threadIdx.x < 32) {
    int i = threadIdx.x;
    int p = pos[s] & (S_ - 1);
    float c = cosT[p * 32 + i], sn = sinT[p * 32 + i];
    float x0 = (float)x[512 + i], x1 = (float)x[544 + i];
    bf16 r0 = (bf16)(x0 * c - x1 * sn);
    bf16 r1 = (bf16)(x0 * sn + x1 * c);
    for (int h = 0; h < NH; ++h) {
      long base = (((long)(b * NH + h)) * S_ + s) * DQK;
      k_bhsd[base + 128 + i] = r0;
      k_bhsd[base + 160 + i] = r1;
    }
  }
}

// ---------------- q scatter: RoPE + SCALE, [NTOK][3072] bf16 -> q_bhsd bf16 ---
__global__ __launch_bounds__(256) void scatter_q(const bf16* __restrict__ q,
                                                 const int* __restrict__ pos,
                                                 const float* __restrict__ cosT,
                                                 const float* __restrict__ sinT,
                                                 bf16* __restrict__ q_bhsd) {
  const float SCALE = 0.07216878364870323f;  // 192^-0.5
  int row = blockIdx.x;
  int b = row / S_, s = row % S_;
  int p = pos[s] & (S_ - 1);
  const bf16* qr = q + (long)row * NQB;
  for (int j = threadIdx.x; j < NQB; j += 256) {
    int h = j / DQK, jj = j - h * DQK;
    float v;
    if (jj < 128) {
      v = (float)qr[j];
    } else if (jj < 160) {
      int i = jj - 128;
      v = (float)qr[h * DQK + 128 + i] * cosT[p * 32 + i] - (float)qr[h * DQK + 160 + i] * sinT[p * 32 + i];
    } else {
      int i = jj - 160;
      v = (float)qr[h * DQK + 128 + i] * sinT[p * 32 + i] + (float)qr[h * DQK + 160 + i] * cosT[p * 32 + i];
    }
    q_bhsd[(((long)(b * NH + h)) * S_ + s) * DQK + jj] = (bf16)(v * SCALE);
  }
}

// ---------------- split k_nope out of kv_b ------------------------------------
__global__ __launch_bounds__(256) void split_k(const bf16* __restrict__ kv_b,
                                               bf16* __restrict__ k_bhsd) {
  int row = blockIdx.x;
  int b = row / S_, s = row % S_;
  for (int j = threadIdx.x; j < 2048; j += 256) {
    int h = j >> 7, d = j & 127;
    k_bhsd[(((long)(b * NH + h)) * S_ + s) * DQK + d] = kv_b[(long)row * NKVB + h * 256 + d];
  }
}

// ---------------- V transpose: kv_b v-part -> v_t [BH][128][S] bf16 -----------
__global__ __launch_bounds__(256) void v_trans(const bf16* __restrict__ kv_b,
                                               bf16* __restrict__ v_t) {
  __shared__ bf16 tile[32][33];
  int st = blockIdx.x, dt = blockIdx.y, bh = blockIdx.z;
  int b = bh >> 4, h = bh & 15;
  int tx = threadIdx.x & 31, ty = threadIdx.x >> 5;
#pragma unroll
  for (int i = 0; i < 4; ++i) {
    int s = st * 32 + ty + i * 8, d = dt * 32 + tx;
    tile[ty + i * 8][tx] = kv_b[((long)(b * S_ + s)) * NKVB + h * 256 + 128 + d];
  }
  __syncthreads();
#pragma unroll
  for (int i = 0; i < 4; ++i) {
    int d = dt * 32 + ty + i * 8, s = st * 32 + tx;
    v_t[((long)bh * DV + d) * S_ + s] = tile[tx][ty + i * 8];
  }
}

// ---------------- flash attention: 1 wave = 16 q rows -------------------------
__global__ __launch_bounds__(64) void flash(const bf16* __restrict__ q_bhsd,
                                            const bf16* __restrict__ k_bhsd,
                                            const bf16* __restrict__ v_t,
                                            bf16* __restrict__ att) {  // [NTOK][2048]
  __shared__ bf16 Plds[16 * 32];
  int blk = blockIdx.x;
  int qt = blk & 127, bh = blk >> 7;
  int b = bh >> 4, h = bh & 15;
  int q0 = qt * 16;
  int l = threadIdx.x;
  int lr = l & 15, lg = l >> 4;

  const bf16* Qb = q_bhsd + (long)bh * S_ * DQK;
  const bf16* Kb = k_bhsd + (long)bh * S_ * DQK;
  const bf16* Vb = v_t + (long)bh * DV * S_;

  bf16x8 qf[6];
#pragma unroll
  for (int t6 = 0; t6 < 6; ++t6)
    qf[t6] = *(const bf16x8*)(Qb + (long)(q0 + lr) * DQK + t6 * 32 + lg * 8);

  f32x4 oacc[8] = {};
  float mrow[4] = {-1e30f, -1e30f, -1e30f, -1e30f};
  float lrow[4] = {0.f, 0.f, 0.f, 0.f};

  int nkt = (q0 + 15) / 32 + 1;
  for (int kt = 0; kt < nkt; ++kt) {
    int k0 = kt * 32;
    f32x4 sacc[2] = {};
#pragma unroll
    for (int n = 0; n < 2; ++n)
#pragma unroll
      for (int t6 = 0; t6 < 6; ++t6) {
        bf16x8 kf = *(const bf16x8*)(Kb + (long)(k0 + n * 16 + lr) * DQK + t6 * 32 + lg * 8);
        sacc[n] = __builtin_amdgcn_mfma_f32_16x16x32_bf16(qf[t6], kf, sacc[n], 0, 0, 0);
      }
    if (k0 + 31 > q0) {
#pragma unroll
      for (int n = 0; n < 2; ++n)
#pragma unroll
        for (int v = 0; v < 4; ++v) {
          int r = lg * 4 + v, c = n * 16 + lr;
          if (k0 + c > q0 + r) sacc[n][v] = -1e30f;
        }
    }
    float corr[4], p0[4], p1[4];
#pragma unroll
    for (int v = 0; v < 4; ++v) {
      float mv = fmaxf(sacc[0][v], sacc[1][v]);
#pragma unroll
      for (int msk = 1; msk < 16; msk <<= 1) mv = fmaxf(mv, __shfl_xor(mv, msk));
      float mt = fmaxf(mrow[v], mv);
      corr[v] = __expf(mrow[v] - mt);
      p0[v] = __expf(sacc[0][v] - mt);
      p1[v] = __expf(sacc[1][v] - mt);
      float ps = p0[v] + p1[v];
#pragma unroll
      for (int msk = 1; msk < 16; msk <<= 1) ps += __shfl_xor(ps, msk);
      lrow[v] = lrow[v] * corr[v] + ps;
      mrow[v] = mt;
    }
#pragma unroll
    for (int n = 0; n < 8; ++n)
#pragma unroll
      for (int v = 0; v < 4; ++v) oacc[n][v] *= corr[v];
#pragma unroll
    for (int v = 0; v < 4; ++v) {
      Plds[(lg * 4 + v) * 32 + lr] = (bf16)p0[v];
      Plds[(lg * 4 + v) * 32 + 16 + lr] = (bf16)p1[v];
    }
    __syncthreads();
    bf16x8 pf = *(const bf16x8*)(Plds + lr * 32 + lg * 8);
#pragma unroll
    for (int n = 0; n < 8; ++n) {
      bf16x8 vf = *(const bf16x8*)(Vb + (long)(n * 16 + lr) * S_ + k0 + lg * 8);
      oacc[n] = __builtin_amdgcn_mfma_f32_16x16x32_bf16(pf, vf, oacc[n], 0, 0, 0);
    }
    __syncthreads();
  }
#pragma unroll
  for (int n = 0; n < 8; ++n)
#pragma unroll
    for (int v = 0; v < 4; ++v) {
      int r = lg * 4 + v;
      float o = oacc[n][v] / lrow[v];
      att[((long)(b * S_ + q0 + r)) * 2048 + h * 128 + n * 16 + lr] = (bf16)o;
    }
}

extern "C" void kernel_launch(void* const* d_in, const int* in_sizes, int n_in,
                              void* d_out, int out_size, void* d_ws, size_t ws_size,
                              hipStream_t stream) {
  const float* x        = (const float*)d_in[0];
  const int* pos        = (const int*)d_in[1];   // harness passes integers as int32
  const float* Wqa      = (const float*)d_in[2];
  const float* g_qa     = (const float*)d_in[3];
  const float* Wqb      = (const float*)d_in[4];
  const float* Wkva     = (const float*)d_in[5];
  const float* g_kva    = (const float*)d_in[6];
  const float* Wkvb     = (const float*)d_in[7];
  const float* Wo       = (const float*)d_in[8];
  const float* cosT     = (const float*)d_in[9];
  const float* sinT     = (const float*)d_in[10];
  float* out            = (float*)d_out;

  // ---- workspace layout (persistent + phase-aliased transient region) ----
  size_t off = 0;
  char* wsp = (char*)d_ws;
  auto alloc = [&](size_t n) { void* p = wsp + off; off += (n + 255) & ~(size_t)255; return p; };
  bf16*  Wqa_t  = (bf16*) alloc((size_t)QR * HD * 2);         // 6.3 MB
  bf16*  Wqb_t  = (bf16*) alloc((size_t)NQB * QR * 2);        // 9.4 MB
  bf16*  Wkva_t = (bf16*) alloc((size_t)640 * HD * 2);        // 2.6 MB
  bf16*  Wkvb_t = (bf16*) alloc((size_t)NKVB * KVR * 2);      // 4.2 MB
  bf16*  Wo_t   = (bf16*) alloc((size_t)HD * HD * 2);         // 8.4 MB
  bf16*  x_bf   = (bf16*) alloc((size_t)NTOK * HD * 2);       // 16.8 MB
  bf16*  q_bhsd = (bf16*) alloc((size_t)B_ * NH * S_ * DQK * 2); // 25.2 MB
  bf16*  k_bhsd = (bf16*) alloc((size_t)B_ * NH * S_ * DQK * 2); // 25.2 MB
  bf16*  v_t    = (bf16*) alloc((size_t)B_ * NH * DV * S_ * 2);  // 16.8 MB
  bf16*  att    = (bf16*) alloc((size_t)NTOK * 2048 * 2);        // 16.8 MB
  char*  T      = (char*) alloc((size_t)50331648);               // 50.3 MB transient
  // Q-phase transients:
  bf16*  q_a = (bf16*)T;                               // 12.6 MB
  bf16*  q_n = (bf16*)(T + 12582912);                  // 12.6 MB
  bf16*  q_f = (bf16*)(T + 25165824);                  // 25.2 MB
  // KV-phase transients (reuse T after q path done):
  bf16*  kv_a = (bf16*)T;                              // 5.3 MB
  bf16*  kv_l = (bf16*)(T + 5242880);                  // 4.2 MB
  bf16*  kv_b = (bf16*)(T + 9437184);                  // 33.6 MB
  if (ws_size < off) return;  // clean fail (absmax) instead of OOB hang

  // 1. x -> bf16
  cvt_bf16<<<(NTOK * HD / 4 + 255) / 256, 256, 0, stream>>>(x, x_bf, (long)NTOK * HD);
  // 2. weight transposes
  transpose_cvt<<<dim3(QR / 32, HD / 32), 256, 0, stream>>>(Wqa, Wqa_t, HD, QR, QR);
  transpose_cvt<<<dim3(NQB / 32, QR / 32), 256, 0, stream>>>(Wqb, Wqb_t, QR, NQB, NQB);
  transpose_cvt<<<dim3(640 / 32, HD / 32), 256, 0, stream>>>(Wkva, Wkva_t, HD, 576, 640);
  transpose_cvt<<<dim3(NKVB / 32, KVR / 32), 256, 0, stream>>>(Wkvb, Wkvb_t, KVR, NKVB, NKVB);
  transpose_cvt<<<dim3(HD / 32, HD / 32), 256, 0, stream>>>(Wo, Wo_t, HD, HD, HD);
  // ---- Q path ----
  gemm_bf16<bf16><<<dim3(QR / 128, NTOK / 128), 256, 0, stream>>>(x_bf, Wqa_t, q_a, NTOK, QR, HD);
  rmsnorm_q<<<NTOK, 256, 0, stream>>>(q_a, g_qa, q_n);
  gemm_bf16<bf16><<<dim3(NQB / 128, NTOK / 128), 256, 0, stream>>>(q_n, Wqb_t, q_f, NTOK, NQB, QR);
  scatter_q<<<NTOK, 256, 0, stream>>>(q_f, pos, cosT, sinT, q_bhsd);
  // ---- KV path (reuses transient region) ----
  gemm_bf16<bf16><<<dim3(640 / 128, NTOK / 128), 256, 0, stream>>>(x_bf, Wkva_t, kv_a, NTOK, 640, HD);
  kv_prep<<<NTOK, 256, 0, stream>>>(kv_a, g_kva, pos, cosT, sinT, kv_l, k_bhsd);
  gemm_bf16<bf16><<<dim3(NKVB / 128, NTOK / 128), 256, 0, stream>>>(kv_l, Wkvb_t, kv_b, NTOK, NKVB, KVR);
  split_k<<<NTOK, 256, 0, stream>>>(kv_b, k_bhsd);
  v_trans<<<dim3(S_ / 32, DV / 32, B_ * NH), 256, 0, stream>>>(kv_b, v_t);
  // ---- attention + output projection ----
  flash<<<B_ * NH * (S_ / 16), 64, 0, stream>>>(q_bhsd, k_bhsd, v_t, att);
  gemm_bf16<float><<<dim3(HD / 128, NTOK / 128), 256, 0, stream>>>(att, Wo_t, out, NTOK, HD, HD);
}

// Round 3
// 434.612 us; speedup vs baseline: 1.9542x; 1.9542x over previous
//
#include <hip/hip_runtime.h>
#include <hip/hip_bf16.h>

typedef __bf16 bf16;
typedef __bf16 bf16x8 __attribute__((ext_vector_type(8)));
typedef float f32x4 __attribute__((ext_vector_type(4)));

#define B_    2
#define S_    2048
#define HD    2048
#define NH    16
#define DQK   192
#define DV    128
#define QR    1536
#define KVR   512
#define NTOK  4096
#define NKVB  4096   /* N_HEADS*(D_NOPE+D_V) */
#define NQB   3072   /* N_HEADS*D_QK */

static __device__ __forceinline__ void gload16(const void* g, void* l) {
  __builtin_amdgcn_global_load_lds(
      (const __attribute__((address_space(1))) void*)g,
      (__attribute__((address_space(3))) void*)l, 16, 0, 0);
}

// ---------------- f32 -> bf16 convert ----------------
__global__ __launch_bounds__(256) void cvt_bf16(const float* __restrict__ in,
                                                bf16* __restrict__ out, long n) {
  long i = ((long)blockIdx.x * 256 + threadIdx.x) * 4;
  if (i + 3 < n) {
    float4 v = *(const float4*)(in + i);
    out[i] = (bf16)v.x; out[i+1] = (bf16)v.y; out[i+2] = (bf16)v.z; out[i+3] = (bf16)v.w;
  }
}

// ---------------- transpose f32 [R][C] -> bf16 [Np][R], zero-pad rows >= C ----
__global__ __launch_bounds__(256) void transpose_cvt(const float* __restrict__ in,
                                                     bf16* __restrict__ out,
                                                     int R, int C, int Np) {
  __shared__ float tile[32][33];
  int c0 = blockIdx.x * 32;
  int r0 = blockIdx.y * 32;
  int tx = threadIdx.x & 31, ty = threadIdx.x >> 5;
#pragma unroll
  for (int i = 0; i < 4; ++i) {
    int r = r0 + ty + i * 8, c = c0 + tx;
    tile[ty + i * 8][tx] = (c < C) ? in[(long)r * C + c] : 0.f;
  }
  __syncthreads();
#pragma unroll
  for (int i = 0; i < 4; ++i) {
    int oc = c0 + ty + i * 8;
    if (oc < Np) out[(long)oc * R + r0 + tx] = (bf16)tile[tx][ty + i * 8];
  }
}

// ---------------- GEMM: C[M][N] = A[M][K] bf16 @ Bt[N][K] bf16 ----------------
template <typename CT>
__global__ __launch_bounds__(256) void gemm_bf16(const bf16* __restrict__ A,
                                                 const bf16* __restrict__ Bt,
                                                 CT* __restrict__ C,
                                                 int M, int N, int K) {
  __shared__ bf16 As[128 * 32];
  __shared__ bf16 Bs[128 * 32];
  const int t = threadIdx.x;
  const int l = t & 63;
  const int w = t >> 6;
  const int m0 = blockIdx.y * 128;
  const int n0 = blockIdx.x * 128;
  const int wr = (w >> 1) * 64;
  const int wc = (w & 1) * 64;
  const int lr = l & 15;
  const int lg = l >> 4;

  f32x4 acc[4][4] = {};

  for (int k0 = 0; k0 < K; k0 += 32) {
    __syncthreads();
#pragma unroll
    for (int j = 0; j < 2; ++j) {
      int c = j * 256 + t;
      int row = c >> 2, kk = (c & 3) * 8;
      bf16* abase = As + (j * 256 + w * 64) * 8;
      bf16* bbase = Bs + (j * 256 + w * 64) * 8;
      gload16(A  + (long)(m0 + row) * K + k0 + kk, abase);
      gload16(Bt + (long)(n0 + row) * K + k0 + kk, bbase);
    }
    __syncthreads();
    bf16x8 af[4], bfr[4];
#pragma unroll
    for (int m = 0; m < 4; ++m)
      af[m] = *(const bf16x8*)(As + (wr + m * 16 + lr) * 32 + lg * 8);
#pragma unroll
    for (int n = 0; n < 4; ++n)
      bfr[n] = *(const bf16x8*)(Bs + (wc + n * 16 + lr) * 32 + lg * 8);
#pragma unroll
    for (int m = 0; m < 4; ++m)
#pragma unroll
      for (int n = 0; n < 4; ++n)
        acc[m][n] = __builtin_amdgcn_mfma_f32_16x16x32_bf16(af[m], bfr[n], acc[m][n], 0, 0, 0);
  }
#pragma unroll
  for (int m = 0; m < 4; ++m)
#pragma unroll
    for (int n = 0; n < 4; ++n)
#pragma unroll
      for (int v = 0; v < 4; ++v) {
        int row = m0 + wr + m * 16 + lg * 4 + v;
        int col = n0 + wc + n * 16 + lr;
        C[(long)row * N + col] = (CT)acc[m][n][v];
      }
}

// ---------------- RMSNorm (q path): [NTOK][QR] bf16 -> bf16 -------------------
__global__ __launch_bounds__(256) void rmsnorm_q(const bf16* __restrict__ in,
                                                 const float* __restrict__ g,
                                                 bf16* __restrict__ out) {
  int row = blockIdx.x;
  const bf16* x = in + (long)row * QR;
  float ss = 0.f;
  for (int j = threadIdx.x; j < QR; j += 256) { float v = (float)x[j]; ss += v * v; }
#pragma unroll
  for (int m = 1; m < 64; m <<= 1) ss += __shfl_xor(ss, m);
  __shared__ float red[4];
  if ((threadIdx.x & 63) == 0) red[threadIdx.x >> 6] = ss;
  __syncthreads();
  ss = red[0] + red[1] + red[2] + red[3];
  float rs = rsqrtf(ss / QR + 1e-5f);
  for (int j = threadIdx.x; j < QR; j += 256)
    out[(long)row * QR + j] = (bf16)((float)x[j] * rs * g[j]);
}

// ---------------- kv prep: RMSNorm latent + RoPE k_rope broadcast -------------
__global__ __launch_bounds__(256) void kv_prep(const bf16* __restrict__ kv_a,  // [NTOK][640]
                                               const float* __restrict__ g,    // [512]
                                               const int* __restrict__ pos,
                                               const float* __restrict__ cosT, // [S][32]
                                               const float* __restrict__ sinT,
                                               bf16* __restrict__ kv_l,        // [NTOK][512]
                                               bf16* __restrict__ k_bhsd) {    // [B][H][S][192]
  int row = blockIdx.x;
  int b = row / S_, s = row % S_;
  const bf16* x = kv_a + (long)row * 640;
  float ss = 0.f;
  for (int j = threadIdx.x; j < KVR; j += 256) { float v = (float)x[j]; ss += v * v; }
#pragma unroll
  for (int m = 1; m < 64; m <<= 1) ss += __shfl_xor(ss, m);
  __shared__ float red[4];
  if ((threadIdx.x & 63) == 0) red[threadIdx.x >> 6] = ss;
  __syncthreads();
  ss = red[0] + red[1] + red[2] + red[3];
  float rs = rsqrtf(ss / KVR + 1e-5f);
  for (int j = threadIdx.x; j < KVR; j += 256)
    kv_l[(long)row * KVR + j] = (bf16)((float)x[j] * rs * g[j]);
  if (threadIdx.x < 32) {
    int i = threadIdx.x;
    int p = pos[s] & (S_ - 1);
    float c = cosT[p * 32 + i], sn = sinT[p * 32 + i];
    float x0 = (float)x[512 + i], x1 = (float)x[544 + i];
    bf16 r0 = (bf16)(x0 * c - x1 * sn);
    bf16 r1 = (bf16)(x0 * sn + x1 * c);
    for (int h = 0; h < NH; ++h) {
      long base = (((long)(b * NH + h)) * S_ + s) * DQK;
      k_bhsd[base + 128 + i] = r0;
      k_bhsd[base + 160 + i] = r1;
    }
  }
}

// ---------------- q scatter: RoPE + SCALE, [NTOK][3072] bf16 -> q_bhsd bf16 ---
__global__ __launch_bounds__(256) void scatter_q(const bf16* __restrict__ q,
                                                 const int* __restrict__ pos,
                                                 const float* __restrict__ cosT,
                                                 const float* __restrict__ sinT,
                                                 bf16* __restrict__ q_bhsd) {
  const float SCALE = 0.07216878364870323f;  // 192^-0.5
  int row = blockIdx.x;
  int b = row / S_, s = row % S_;
  int p = pos[s] & (S_ - 1);
  const bf16* qr = q + (long)row * NQB;
  for (int j = threadIdx.x; j < NQB; j += 256) {
    int h = j / DQK, jj = j - h * DQK;
    float v;
    if (jj < 128) {
      v = (float)qr[j];
    } else if (jj < 160) {
      int i = jj - 128;
      v = (float)qr[h * DQK + 128 + i] * cosT[p * 32 + i] - (float)qr[h * DQK + 160 + i] * sinT[p * 32 + i];
    } else {
      int i = jj - 160;
      v = (float)qr[h * DQK + 128 + i] * sinT[p * 32 + i] + (float)qr[h * DQK + 160 + i] * cosT[p * 32 + i];
    }
    q_bhsd[(((long)(b * NH + h)) * S_ + s) * DQK + jj] = (bf16)(v * SCALE);
  }
}

// ---------------- split k_nope out of kv_b ------------------------------------
__global__ __launch_bounds__(256) void split_k(const bf16* __restrict__ kv_b,
                                               bf16* __restrict__ k_bhsd) {
  int row = blockIdx.x;
  int b = row / S_, s = row % S_;
  for (int j = threadIdx.x; j < 2048; j += 256) {
    int h = j >> 7, d = j & 127;
    k_bhsd[(((long)(b * NH + h)) * S_ + s) * DQK + d] = kv_b[(long)row * NKVB + h * 256 + d];
  }
}

// ---------------- V transpose: kv_b v-part -> v_t [BH][128][S] bf16 -----------
__global__ __launch_bounds__(256) void v_trans(const bf16* __restrict__ kv_b,
                                               bf16* __restrict__ v_t) {
  __shared__ bf16 tile[32][33];
  int st = blockIdx.x, dt = blockIdx.y, bh = blockIdx.z;
  int b = bh >> 4, h = bh & 15;
  int tx = threadIdx.x & 31, ty = threadIdx.x >> 5;
#pragma unroll
  for (int i = 0; i < 4; ++i) {
    int s = st * 32 + ty + i * 8, d = dt * 32 + tx;
    tile[ty + i * 8][tx] = kv_b[((long)(b * S_ + s)) * NKVB + h * 256 + 128 + d];
  }
  __syncthreads();
#pragma unroll
  for (int i = 0; i < 4; ++i) {
    int d = dt * 32 + ty + i * 8, s = st * 32 + tx;
    v_t[((long)bh * DV + d) * S_ + s] = tile[tx][ty + i * 8];
  }
}

// ---------------- flash attention v2: 4 waves, QBLK=64, KVBLK=64, LDS-staged --
// K tile [64][192] and V tile [128][64] staged via global_load_lds with
// both-sides XOR chunk swizzle (chunk ^ (row&7)); P per-wave [16][72] padded.
#define QBLK 64
#define KVB  64
__global__ __launch_bounds__(256) void flash2(const bf16* __restrict__ q_bhsd,
                                              const bf16* __restrict__ k_bhsd,
                                              const bf16* __restrict__ v_t,
                                              bf16* __restrict__ att) {  // [NTOK][2048]
  __shared__ bf16 Ks[KVB * DQK];      // 24 KB, swizzled 16B chunks
  __shared__ bf16 Vs[DV * KVB];       // 16 KB, swizzled 16B chunks
  __shared__ bf16 Ps[4][16 * 72];     // 9 KB, per-wave P, padded to 72
  int bid = blockIdx.x;
  int bh = bid & 31;                  // head-of-batch: fixes XCD = bh%8
  int qt = 31 - (bid >> 5);           // heaviest (most k-tiles) first
  int b = bh >> 4, h = bh & 15;
  int q0 = qt * QBLK;
  int t = threadIdx.x;
  int w = t >> 6, l = t & 63;
  int lr = l & 15, lg = l >> 4;
  int qw = q0 + w * 16;               // this wave's first q row

  const bf16* Qb = q_bhsd + (long)bh * S_ * DQK;
  const bf16* Kb = k_bhsd + (long)bh * S_ * DQK;
  const bf16* Vb = v_t + (long)bh * DV * S_;

  bf16x8 qf[6];
#pragma unroll
  for (int t6 = 0; t6 < 6; ++t6)
    qf[t6] = *(const bf16x8*)(Qb + (long)(qw + lr) * DQK + t6 * 32 + lg * 8);

  f32x4 oacc[8] = {};
  float mrow[4] = {-1e30f, -1e30f, -1e30f, -1e30f};
  float lrow[4] = {0.f, 0.f, 0.f, 0.f};
  const int lr7 = lr & 7;

  int nkt = qt + 1;
  for (int kt = 0; kt < nkt; ++kt) {
    int k0 = kt * KVB;
    __syncthreads();
    // stage K: 1536 chunks (6 x 256); slot s holds global chunk (r, c^(r&7))
#pragma unroll
    for (int j = 0; j < 6; ++j) {
      int s = j * 256 + t;
      int r = s / 24, c1 = s - r * 24;
      int c = c1 ^ (r & 7);
      gload16(Kb + (long)(k0 + r) * DQK + c * 8, Ks + (j * 256 + w * 64) * 8);
    }
    // stage V: 1024 chunks (4 x 256)
#pragma unroll
    for (int j = 0; j < 4; ++j) {
      int s = j * 256 + t;
      int d = s >> 3, c1 = s & 7;
      int c = c1 ^ (d & 7);
      gload16(Vb + (long)d * S_ + k0 + c * 8, Vs + (j * 256 + w * 64) * 8);
    }
    __syncthreads();
    if (k0 > qw + 15) continue;       // fully masked for this wave (both barriers already hit)

    // ---- QK^T: sacc[n] = scores[q=lg*4+v][k=n*16+lr] ----
    f32x4 sacc[4] = {};
#pragma unroll
    for (int n = 0; n < 4; ++n) {
      int rk = n * 16 + lr;
#pragma unroll
      for (int t6 = 0; t6 < 6; ++t6) {
        bf16x8 kf = *(const bf16x8*)(Ks + rk * DQK + (((t6 * 4 + lg) ^ lr7) << 3));
        sacc[n] = __builtin_amdgcn_mfma_f32_16x16x32_bf16(qf[t6], kf, sacc[n], 0, 0, 0);
      }
    }
    // ---- causal mask (diagonal tiles only) ----
    if (k0 + KVB - 1 > qw) {
#pragma unroll
      for (int n = 0; n < 4; ++n)
#pragma unroll
        for (int v = 0; v < 4; ++v) {
          int r = lg * 4 + v, c = n * 16 + lr;
          if (k0 + c > qw + r) sacc[n][v] = -1e30f;
        }
    }
    // ---- online softmax ----
    float corr[4], p[4][4];
#pragma unroll
    for (int v = 0; v < 4; ++v) {
      float mv = fmaxf(fmaxf(sacc[0][v], sacc[1][v]), fmaxf(sacc[2][v], sacc[3][v]));
#pragma unroll
      for (int msk = 1; msk < 16; msk <<= 1) mv = fmaxf(mv, __shfl_xor(mv, msk));
      float mt = fmaxf(mrow[v], mv);
      corr[v] = __expf(mrow[v] - mt);
      float ps = 0.f;
#pragma unroll
      for (int n = 0; n < 4; ++n) { p[n][v] = __expf(sacc[n][v] - mt); ps += p[n][v]; }
#pragma unroll
      for (int msk = 1; msk < 16; msk <<= 1) ps += __shfl_xor(ps, msk);
      lrow[v] = lrow[v] * corr[v] + ps;
      mrow[v] = mt;
    }
#pragma unroll
    for (int dn = 0; dn < 8; ++dn)
#pragma unroll
      for (int v = 0; v < 4; ++v) oacc[dn][v] *= corr[v];
    // ---- P -> LDS (per-wave, padded) ----
#pragma unroll
    for (int v = 0; v < 4; ++v)
#pragma unroll
      for (int n = 0; n < 4; ++n)
        Ps[w][(lg * 4 + v) * 72 + n * 16 + lr] = (bf16)p[n][v];
    // ---- PV: oacc[dn] += P[16x64] @ V^T[d=dn*16+lr][k] ----
#pragma unroll
    for (int kc = 0; kc < 2; ++kc) {
      bf16x8 pf = *(const bf16x8*)(Ps[w] + lr * 72 + kc * 32 + lg * 8);
#pragma unroll
      for (int dn = 0; dn < 8; ++dn) {
        int d = dn * 16 + lr;
        bf16x8 vf = *(const bf16x8*)(Vs + d * KVB + (((kc * 4 + lg) ^ lr7) << 3));
        oacc[dn] = __builtin_amdgcn_mfma_f32_16x16x32_bf16(pf, vf, oacc[dn], 0, 0, 0);
      }
    }
  }
  // ---- epilogue ----
#pragma unroll
  for (int dn = 0; dn < 8; ++dn)
#pragma unroll
    for (int v = 0; v < 4; ++v) {
      int r = lg * 4 + v;
      float o = oacc[dn][v] / lrow[v];
      att[((long)(b * S_ + qw + r)) * 2048 + h * 128 + dn * 16 + lr] = (bf16)o;
    }
}

extern "C" void kernel_launch(void* const* d_in, const int* in_sizes, int n_in,
                              void* d_out, int out_size, void* d_ws, size_t ws_size,
                              hipStream_t stream) {
  const float* x        = (const float*)d_in[0];
  const int* pos        = (const int*)d_in[1];   // harness passes integers as int32
  const float* Wqa      = (const float*)d_in[2];
  const float* g_qa     = (const float*)d_in[3];
  const float* Wqb      = (const float*)d_in[4];
  const float* Wkva     = (const float*)d_in[5];
  const float* g_kva    = (const float*)d_in[6];
  const float* Wkvb     = (const float*)d_in[7];
  const float* Wo       = (const float*)d_in[8];
  const float* cosT     = (const float*)d_in[9];
  const float* sinT     = (const float*)d_in[10];
  float* out            = (float*)d_out;

  // ---- workspace layout (persistent + phase-aliased transient region) ----
  size_t off = 0;
  char* wsp = (char*)d_ws;
  auto alloc = [&](size_t n) { void* p = wsp + off; off += (n + 255) & ~(size_t)255; return p; };
  bf16*  Wqa_t  = (bf16*) alloc((size_t)QR * HD * 2);
  bf16*  Wqb_t  = (bf16*) alloc((size_t)NQB * QR * 2);
  bf16*  Wkva_t = (bf16*) alloc((size_t)640 * HD * 2);
  bf16*  Wkvb_t = (bf16*) alloc((size_t)NKVB * KVR * 2);
  bf16*  Wo_t   = (bf16*) alloc((size_t)HD * HD * 2);
  bf16*  x_bf   = (bf16*) alloc((size_t)NTOK * HD * 2);
  bf16*  q_bhsd = (bf16*) alloc((size_t)B_ * NH * S_ * DQK * 2);
  bf16*  k_bhsd = (bf16*) alloc((size_t)B_ * NH * S_ * DQK * 2);
  bf16*  v_t    = (bf16*) alloc((size_t)B_ * NH * DV * S_ * 2);
  bf16*  att    = (bf16*) alloc((size_t)NTOK * 2048 * 2);
  char*  T      = (char*) alloc((size_t)50331648);
  bf16*  q_a = (bf16*)T;
  bf16*  q_n = (bf16*)(T + 12582912);
  bf16*  q_f = (bf16*)(T + 25165824);
  bf16*  kv_a = (bf16*)T;
  bf16*  kv_l = (bf16*)(T + 5242880);
  bf16*  kv_b = (bf16*)(T + 9437184);
  if (ws_size < off) return;

  cvt_bf16<<<(NTOK * HD / 4 + 255) / 256, 256, 0, stream>>>(x, x_bf, (long)NTOK * HD);
  transpose_cvt<<<dim3(QR / 32, HD / 32), 256, 0, stream>>>(Wqa, Wqa_t, HD, QR, QR);
  transpose_cvt<<<dim3(NQB / 32, QR / 32), 256, 0, stream>>>(Wqb, Wqb_t, QR, NQB, NQB);
  transpose_cvt<<<dim3(640 / 32, HD / 32), 256, 0, stream>>>(Wkva, Wkva_t, HD, 576, 640);
  transpose_cvt<<<dim3(NKVB / 32, KVR / 32), 256, 0, stream>>>(Wkvb, Wkvb_t, KVR, NKVB, NKVB);
  transpose_cvt<<<dim3(HD / 32, HD / 32), 256, 0, stream>>>(Wo, Wo_t, HD, HD, HD);
  // ---- Q path ----
  gemm_bf16<bf16><<<dim3(QR / 128, NTOK / 128), 256, 0, stream>>>(x_bf, Wqa_t, q_a, NTOK, QR, HD);
  rmsnorm_q<<<NTOK, 256, 0, stream>>>(q_a, g_qa, q_n);
  gemm_bf16<bf16><<<dim3(NQB / 128, NTOK / 128), 256, 0, stream>>>(q_n, Wqb_t, q_f, NTOK, NQB, QR);
  scatter_q<<<NTOK, 256, 0, stream>>>(q_f, pos, cosT, sinT, q_bhsd);
  // ---- KV path (reuses transient region) ----
  gemm_bf16<bf16><<<dim3(640 / 128, NTOK / 128), 256, 0, stream>>>(x_bf, Wkva_t, kv_a, NTOK, 640, HD);
  kv_prep<<<NTOK, 256, 0, stream>>>(kv_a, g_kva, pos, cosT, sinT, kv_l, k_bhsd);
  gemm_bf16<bf16><<<dim3(NKVB / 128, NTOK / 128), 256, 0, stream>>>(kv_l, Wkvb_t, kv_b, NTOK, NKVB, KVR);
  split_k<<<NTOK, 256, 0, stream>>>(kv_b, k_bhsd);
  v_trans<<<dim3(S_ / 32, DV / 32, B_ * NH), 256, 0, stream>>>(kv_b, v_t);
  // ---- attention + output projection ----
  flash2<<<1024, 256, 0, stream>>>(q_bhsd, k_bhsd, v_t, att);
  gemm_bf16<float><<<dim3(HD / 128, NTOK / 128), 256, 0, stream>>>(att, Wo_t, out, NTOK, HD, HD);
}